// Round 3
// baseline (630.908 us; speedup 1.0000x reference)
//
#include <hip/hip_runtime.h>
#include <cstdint>
#include <cstddef>

#define MDIM 8192
#define NDIM 4096
#define KDIM 4096

typedef __attribute__((ext_vector_type(8))) __bf16 bf16x8;
typedef __attribute__((ext_vector_type(4))) float floatx4;

typedef __attribute__((address_space(3))) void lds_t;
typedef __attribute__((address_space(1))) void glb_t;

__device__ __forceinline__ unsigned short f32_to_bf16(float f) {
  unsigned int u = __float_as_uint(f);
  u += 0x7FFFu + ((u >> 16) & 1u);   // RNE
  return (unsigned short)(u >> 16);
}

// e2m1 magnitude for code c in 0..7: {0,0.5,1,1.5,2,3,4,6}
__device__ __forceinline__ float fp4_mag(int c) {
  int e = (c >> 1) & 3, m = c & 1;
  int sh = e ? (e - 1) : 0;
  return e ? 0.5f * (float)((2 + m) << sh) : 0.5f * (float)m;
}

// ---------------- prepass: dequant weights -> bf16 [N][K] ----------------
// thread t handles one 16-element scale block = 8 packed bytes (1 byte/int32)
__global__ __launch_bounds__(256) void dequant_kernel(const int* __restrict__ packed,
                                                      const float* __restrict__ scales,
                                                      unsigned short* __restrict__ wb) {
  const int t = blockIdx.x * 256 + threadIdx.x;     // 0 .. 1048575
  const int4* p = (const int4*)packed + (size_t)t * 2;
  int4 pa = p[0], pb = p[1];
  float s = scales[t];
  int bytes[8] = {pa.x, pa.y, pa.z, pa.w, pb.x, pb.y, pb.z, pb.w};
  union { unsigned short us[16]; uint4 u4[2]; } o;
#pragma unroll
  for (int i = 0; i < 8; ++i) {
    int by = bytes[i] & 255;
    int hi = by >> 4, lo = by & 15;                 // even idx = high nibble
    float vh = fp4_mag(hi & 7) * s; if (hi & 8) vh = -vh;
    float vl = fp4_mag(lo & 7) * s; if (lo & 8) vl = -vl;
    o.us[2 * i]     = f32_to_bf16(vh);
    o.us[2 * i + 1] = f32_to_bf16(vl);
  }
  uint4* dst = (uint4*)(wb + (size_t)t * 16);
  dst[0] = o.u4[0]; dst[1] = o.u4[1];
}

// ---------------- main GEMM: C[M,N] = A_f32[M,K] * B_bf16[N,K]^T + bias ------
// 128x128 block tile, BK=32, 4 waves x (4x4) 16x16x32 bf16 MFMA.
// A staged as fp32 via global_load_lds (16KB, XOR-swizzled 16B chunks so the
// fragment reads stay bank-balanced); converted to bf16 at fragment read.
// B staged bf16 (8KB) as in round 1.
__global__ __launch_bounds__(256, 3) void gemm_kernel(const float* __restrict__ A,
                                                      const __bf16* __restrict__ B,
                                                      const float* __restrict__ bias,
                                                      float* __restrict__ C) {
  __shared__ float As[128 * 32];     // fp32 A tile, rows of 32 floats (128B)
  __shared__ __bf16 Bs[128 * 32];    // bf16 B tile, rows of 32 bf16 (64B)
  const int t = threadIdx.x;
  const int wave = t >> 6, lane = t & 63;
  const int quad = lane >> 4, r16 = lane & 15;
  const int wm = (wave >> 1) * 64, wn = (wave & 1) * 64;
  const int m0 = blockIdx.y * 128, n0 = blockIdx.x * 128;

  floatx4 acc[4][4] = {};

  // ---- A staging map (4 calls q=0..3): thread t -> LDS byte q*4096 + t*16,
  //      i.e. row ra = q*32 + (t>>3), physical chunk t&7.  The physical chunk
  //      holds logical chunk (t&7) ^ (ra&7)  (XOR swizzle, self-inverse).
  const int ar = t >> 3;                       // row within 32-row group
  const int ac = ((t & 7) ^ (ar & 7)) * 4;     // swizzled float column
  const float* ga = A + (size_t)(m0 + ar) * KDIM + ac;

  // ---- B staging map: thread t -> row t>>2, bf16 col (t&3)*8 (as round 1)
  const int sr = t >> 2;
  const int sc = (t & 3) * 8;
  const __bf16* gb = B + (size_t)(n0 + sr) * KDIM + sc;

  // fragment-read swizzled chunk (row&7 == r16&7 since wm, i*16 are mult of 8... 16)
  const int c0 = ((quad * 2) ^ (r16 & 7));     // logical chunk quad*2 lives here

  for (int k0 = 0; k0 < KDIM; k0 += 32) {
#pragma unroll
    for (int q = 0; q < 4; ++q)
      __builtin_amdgcn_global_load_lds((const glb_t*)(ga + (size_t)q * 32 * KDIM),
                                       (lds_t*)(As + q * 1024 + wave * 256), 16, 0, 0);
    __builtin_amdgcn_global_load_lds((const glb_t*)(gb),
                                     (lds_t*)(Bs + wave * 512), 16, 0, 0);
    __builtin_amdgcn_global_load_lds((const glb_t*)(gb + (size_t)64 * KDIM),
                                     (lds_t*)(Bs + 2048 + wave * 512), 16, 0, 0);
    ga += 32; gb += 32;
    __syncthreads();

    bf16x8 af[4], bfr[4];
#pragma unroll
    for (int i = 0; i < 4; ++i) {
      // A-operand: lane holds A[m = wm+i*16+r16][k = quad*8 + j], j=0..7
      const float* arow = As + (wm + i * 16 + r16) * 32;
      floatx4 f0 = *(const floatx4*)(arow + c0 * 4);
      floatx4 f1 = *(const floatx4*)(arow + (c0 ^ 1) * 4);
      bf16x8 a;
      a[0] = (__bf16)f0[0]; a[1] = (__bf16)f0[1];
      a[2] = (__bf16)f0[2]; a[3] = (__bf16)f0[3];
      a[4] = (__bf16)f1[0]; a[5] = (__bf16)f1[1];
      a[6] = (__bf16)f1[2]; a[7] = (__bf16)f1[3];
      af[i] = a;
      // B-operand: lane holds B[k = quad*8+j][n = lane&15] = w[n][k]
      bfr[i] = *(const bf16x8*)(Bs + (wn + i * 16 + r16) * 32 + quad * 8);
    }
#pragma unroll
    for (int i = 0; i < 4; ++i)
#pragma unroll
      for (int j = 0; j < 4; ++j)
        acc[i][j] = __builtin_amdgcn_mfma_f32_16x16x32_bf16(af[i], bfr[j], acc[i][j], 0, 0, 0);
    __syncthreads();
  }

  // epilogue: C/D layout col = lane&15, row = quad*4 + reg
  float bv[4];
#pragma unroll
  for (int j = 0; j < 4; ++j) bv[j] = bias[n0 + wn + j * 16 + r16];
#pragma unroll
  for (int i = 0; i < 4; ++i) {
    const int gm = m0 + wm + i * 16 + quad * 4;
#pragma unroll
    for (int j = 0; j < 4; ++j) {
      float* cp = C + (size_t)gm * NDIM + (n0 + wn + j * 16 + r16);
#pragma unroll
      for (int r = 0; r < 4; ++r)
        cp[(size_t)r * NDIM] = acc[i][j][r] + bv[j];
    }
  }
}

// ---------------- fallback (ws too small): fused naive ----------------
__global__ __launch_bounds__(256) void fused_fallback(const float* __restrict__ x,
                                                      const int* __restrict__ packed,
                                                      const float* __restrict__ scales,
                                                      const float* __restrict__ bias,
                                                      float* __restrict__ out) {
  const int n = blockIdx.x * 256 + threadIdx.x;
  const int m = blockIdx.y;
  const float* xr = x + (size_t)m * KDIM;
  const int* pr = packed + (size_t)n * (KDIM / 2);
  const float* sc = scales + (size_t)n * (KDIM / 16);
  float acc = 0.f;
  for (int kb = 0; kb < KDIM / 16; ++kb) {
    float s = sc[kb];
    float part = 0.f;
#pragma unroll
    for (int i = 0; i < 8; ++i) {
      int by = pr[kb * 8 + i] & 255;
      int hi = by >> 4, lo = by & 15;
      float vh = fp4_mag(hi & 7); if (hi & 8) vh = -vh;
      float vl = fp4_mag(lo & 7); if (lo & 8) vl = -vl;
      part += xr[kb * 16 + 2 * i] * vh + xr[kb * 16 + 2 * i + 1] * vl;
    }
    acc += s * part;
  }
  out[(size_t)m * NDIM + n] = acc + bias[n];
}

extern "C" void kernel_launch(void* const* d_in, const int* in_sizes, int n_in,
                              void* d_out, int out_size, void* d_ws, size_t ws_size,
                              hipStream_t stream) {
  const float* x      = (const float*)d_in[0];
  const int*   packed = (const int*)d_in[1];
  const float* scales = (const float*)d_in[2];
  const float* bias   = (const float*)d_in[3];
  float* out = (float*)d_out;

  const size_t needW = (size_t)NDIM * KDIM * 2;   // 32 MB bf16 w

  if (ws_size >= needW) {
    unsigned short* wb = (unsigned short*)d_ws;
    dequant_kernel<<<(NDIM * KDIM / 16) / 256, 256, 0, stream>>>(packed, scales, wb);
    dim3 grid(NDIM / 128, MDIM / 128);
    gemm_kernel<<<grid, 256, 0, stream>>>(x, (const __bf16*)wb, bias, out);
  } else {
    dim3 grid(NDIM / 256, MDIM);
    fused_fallback<<<grid, 256, 0, stream>>>(x, packed, scales, bias, out);
  }
}